// Round 1
// baseline (546.105 us; speedup 1.0000x reference)
//
#include <hip/hip_runtime.h>
#include <cstdint>
#include <cstddef>

#define B_ 256
#define S_ 128
#define H_ 512
#define E_ 512
#define V_ 32000

typedef _Float16 half_t;
typedef _Float16 half8 __attribute__((ext_vector_type(8)));
typedef _Float16 half4v __attribute__((ext_vector_type(4)));
typedef float floatx4 __attribute__((ext_vector_type(4)));

__device__ __forceinline__ float sigmoidf_(float x) { return 1.0f / (1.0f + __expf(-x)); }

// ---------------------------------------------------------------------------
// prep: build x = [embed[ids], weighted_eff] (B,1536) and prev_eff (B,512),
// honoring the order==0 branch (recompute prev from encoded[:, -1] @ Ws_w.T).
// ---------------------------------------------------------------------------
__global__ __launch_bounds__(256)
void prep_kernel(const int* __restrict__ ids, const float* __restrict__ encoded,
                 const float* __restrict__ prev_state, const float* __restrict__ weighted,
                 const int* __restrict__ order_p, const float* __restrict__ embed,
                 const float* __restrict__ Ws_w, const float* __restrict__ Ws_b,
                 float* __restrict__ x, float* __restrict__ prev)
{
    int i = blockIdx.x * 256 + threadIdx.x;   // B_ * 2048 threads
    int b = i >> 11;
    int j = i & 2047;
    int order = order_p[0];
    if (j < 1536) {
        float v;
        if (j < 512) v = embed[(size_t)ids[b] * E_ + j];
        else         v = (order == 0) ? 0.0f : weighted[b * 1024 + (j - 512)];
        x[b * 1536 + j] = v;
    } else {
        int h = j - 1536;
        float v;
        if (order != 0) {
            v = prev_state[b * H_ + h];
        } else {
            const float* e  = encoded + ((size_t)b * S_ + (S_ - 1)) * 1024;
            const float* wr = Ws_w + (size_t)h * 1024;
            float accv = Ws_b[h];
            for (int k = 0; k < 1024; ++k) accv += e[k] * wr[k];
            v = accv;
        }
        prev[b * H_ + h] = v;
    }
}

// ---------------------------------------------------------------------------
// Generic fp32-in / fp16-MFMA GEMM:  C[m,n] = sum_k A[m,k] * Bw[n,k]  (+bias)
// EPI==0 : write C + bias
// EPI==1 : fused tanh-einsum epilogue (C1): per row m (= b*S+s),
//          sc_out[m] += sum_n tanh(acc+bias[n]) * hidden[b,n]   (atomic)
// M, N must be multiples of the block tile; K multiple of 32 (all exact here).
// ---------------------------------------------------------------------------
template<int BM, int BN, int WAVES_M, int WAVES_N, int EPI>
__global__ __launch_bounds__(256)
void gemm_f16(const float* __restrict__ A, const float* __restrict__ Bw,
              float* __restrict__ C, const float* __restrict__ bias,
              const float* __restrict__ hidden, float* __restrict__ sc_out,
              int K, int lda, int ldb, int ldc)
{
    constexpr int BK  = 32;
    constexpr int LDP = BK + 8;            // padded LDS stride (halves)
    constexpr int WM  = BM / WAVES_M;
    constexpr int WN  = BN / WAVES_N;
    constexpr int FM  = WM / 16;
    constexpr int FN  = WN / 16;
    constexpr int A_IT = (BM * 8) / 256;   // float4 loads per thread for A tile
    constexpr int B_IT = (BN * 8) / 256;
    static_assert(BM % (WAVES_M * 16) == 0 && BN % (WAVES_N * 16) == 0, "tile");

    __shared__ half_t As[BM * LDP];
    __shared__ half_t Bs[BN * LDP];

    const int tid  = threadIdx.x;
    const int wid  = tid >> 6;
    const int lane = tid & 63;
    const int wm   = wid % WAVES_M;
    const int wn   = wid / WAVES_M;
    const int bm0  = blockIdx.y * BM;
    const int bn0  = blockIdx.x * BN;
    const int col  = lane & 15;
    const int quad = lane >> 4;

    floatx4 acc[FM][FN] = {};

    for (int kt = 0; kt < K; kt += BK) {
        float4 areg[A_IT], breg[B_IT];
#pragma unroll
        for (int i = 0; i < A_IT; ++i) {
            int idx = tid + i * 256;
            int row = idx >> 3, c4 = (idx & 7) << 2;
            areg[i] = *(const float4*)(A + (size_t)(bm0 + row) * lda + kt + c4);
        }
#pragma unroll
        for (int i = 0; i < B_IT; ++i) {
            int idx = tid + i * 256;
            int row = idx >> 3, c4 = (idx & 7) << 2;
            breg[i] = *(const float4*)(Bw + (size_t)(bn0 + row) * ldb + kt + c4);
        }
        __syncthreads();   // previous iteration's LDS reads complete
#pragma unroll
        for (int i = 0; i < A_IT; ++i) {
            int idx = tid + i * 256;
            int row = idx >> 3, c4 = (idx & 7) << 2;
            half4v h;
            h[0] = (half_t)areg[i].x; h[1] = (half_t)areg[i].y;
            h[2] = (half_t)areg[i].z; h[3] = (half_t)areg[i].w;
            *(half4v*)(&As[row * LDP + c4]) = h;
        }
#pragma unroll
        for (int i = 0; i < B_IT; ++i) {
            int idx = tid + i * 256;
            int row = idx >> 3, c4 = (idx & 7) << 2;
            half4v h;
            h[0] = (half_t)breg[i].x; h[1] = (half_t)breg[i].y;
            h[2] = (half_t)breg[i].z; h[3] = (half_t)breg[i].w;
            *(half4v*)(&Bs[row * LDP + c4]) = h;
        }
        __syncthreads();

        half8 af[FM], bf[FN];
#pragma unroll
        for (int fm = 0; fm < FM; ++fm)
            af[fm] = *(const half8*)(&As[(wm * WM + fm * 16 + col) * LDP + quad * 8]);
#pragma unroll
        for (int fn = 0; fn < FN; ++fn)
            bf[fn] = *(const half8*)(&Bs[(wn * WN + fn * 16 + col) * LDP + quad * 8]);
#pragma unroll
        for (int fm = 0; fm < FM; ++fm)
#pragma unroll
            for (int fn = 0; fn < FN; ++fn)
                acc[fm][fn] = __builtin_amdgcn_mfma_f32_16x16x32_f16(af[fm], bf[fn], acc[fm][fn], 0, 0, 0);
    }

    if constexpr (EPI == 0) {
#pragma unroll
        for (int fm = 0; fm < FM; ++fm) {
            int m0 = bm0 + wm * WM + fm * 16 + quad * 4;
#pragma unroll
            for (int fn = 0; fn < FN; ++fn) {
                int n = bn0 + wn * WN + fn * 16 + col;
                float bv = bias[n];
#pragma unroll
                for (int r = 0; r < 4; ++r)
                    C[(size_t)(m0 + r) * ldc + n] = acc[fm][fn][r] + bv;
            }
        }
    } else {
        // all BM=128 rows of this block belong to one batch b = bm0 / 128
        const float* hid = hidden + (size_t)(bm0 >> 7) * H_;
#pragma unroll
        for (int fm = 0; fm < FM; ++fm) {
            float p0 = 0.f, p1 = 0.f, p2 = 0.f, p3 = 0.f;
#pragma unroll
            for (int fn = 0; fn < FN; ++fn) {
                int n = bn0 + wn * WN + fn * 16 + col;
                float bv = bias[n];
                float hv = hid[n];
                p0 += tanhf(acc[fm][fn][0] + bv) * hv;
                p1 += tanhf(acc[fm][fn][1] + bv) * hv;
                p2 += tanhf(acc[fm][fn][2] + bv) * hv;
                p3 += tanhf(acc[fm][fn][3] + bv) * hv;
            }
#pragma unroll
            for (int off = 1; off < 16; off <<= 1) {   // reduce over 16 cols
                p0 += __shfl_xor(p0, off, 64);
                p1 += __shfl_xor(p1, off, 64);
                p2 += __shfl_xor(p2, off, 64);
                p3 += __shfl_xor(p3, off, 64);
            }
            if (col == 0) {
                int m0 = bm0 + wm * WM + fm * 16 + quad * 4;
                atomicAdd(&sc_out[m0 + 0], p0);
                atomicAdd(&sc_out[m0 + 1], p1);
                atomicAdd(&sc_out[m0 + 2], p2);
                atomicAdd(&sc_out[m0 + 3], p3);
            }
        }
    }
}

// ---------------------------------------------------------------------------
// GRU gates: hidden = (1-z)*n + z*prev
// ---------------------------------------------------------------------------
__global__ __launch_bounds__(256)
void gate_kernel(const float* __restrict__ gi, const float* __restrict__ gh,
                 const float* __restrict__ prev, float* __restrict__ hidden)
{
    int i = blockIdx.x * 256 + threadIdx.x;   // B_*H_
    int b = i >> 9;
    int h = i & 511;
    const float* gib = gi + (size_t)b * 1536;
    const float* ghb = gh + (size_t)b * 1536;
    float r = sigmoidf_(gib[h] + ghb[h]);
    float z = sigmoidf_(gib[h + 512] + ghb[h + 512]);
    float n = tanhf(gib[h + 1024] + r * ghb[h + 1024]);
    hidden[i] = (1.0f - z) * n + z * prev[i];
}

// ---------------------------------------------------------------------------
// final: per-row (b) softmax over [score_g (V) | tanh(sc_raw+mask) (S)],
// writes prob_g to predicted, scatter-adds prob_c at src, computes
// weighted_out = sum_s attn[s]*encoded[b,s,:].
// ---------------------------------------------------------------------------
__global__ __launch_bounds__(256)
void final_kernel(const float* __restrict__ score_g, const float* __restrict__ sc_raw,
                  const int* __restrict__ src, const int* __restrict__ ids,
                  const float* __restrict__ encoded,
                  float* __restrict__ predicted, float* __restrict__ weighted_out)
{
    int b = blockIdx.x;
    int t = threadIdx.x;
    __shared__ float s_scf[S_];
    __shared__ float s_attn[S_];
    __shared__ int   s_src[S_];
    __shared__ float rm[4], rs[4];
    __shared__ int   s_cnt;

    const float* sg = score_g + (size_t)b * V_;
    float* pred = predicted + (size_t)b * V_;

    if (t < S_) {
        int sv = src[b * S_ + t];
        s_src[t] = sv;
        float raw = sc_raw[b * S_ + t];
        if (sv == 0) raw -= 1000.0f;
        s_scf[t] = tanhf(raw);
    }
    __syncthreads();

    // online (max, sumexp) over this thread's strided elements
    float m = -1e30f, s = 0.f;
    for (int v = t; v < V_; v += 256) {
        float x = sg[v];
        float mn = fmaxf(m, x);
        s = s * __expf(m - mn) + __expf(x - mn);
        m = mn;
    }
    if (t < S_) {
        float x = s_scf[t];
        float mn = fmaxf(m, x);
        s = s * __expf(m - mn) + __expf(x - mn);
        m = mn;
    }
    // wave butterfly reduce of (m,s)
#pragma unroll
    for (int off = 1; off < 64; off <<= 1) {
        float mo = __shfl_xor(m, off, 64);
        float so = __shfl_xor(s, off, 64);
        float mn = fmaxf(m, mo);
        s = s * __expf(m - mn) + so * __expf(mo - mn);
        m = mn;
    }
    if ((t & 63) == 0) { rm[t >> 6] = m; rs[t >> 6] = s; }
    __syncthreads();
    float M = rm[0], Z = rs[0];
#pragma unroll
    for (int w = 1; w < 4; ++w) {
        float mo = rm[w], so = rs[w];
        float mn = fmaxf(M, mo);
        Z = Z * __expf(M - mn) + so * __expf(mo - mn);
        M = mn;
    }
    float invZ = 1.0f / Z;

    // write prob_g
    for (int v = t; v < V_; v += 256)
        pred[v] = __expf(sg[v] - M) * invZ;

    int ii = ids[b];
    if (t == 0) {
        int c = 0;
        for (int s2 = 0; s2 < S_; ++s2) c += (s_src[s2] == ii) ? 1 : 0;
        s_cnt = (c > 0) ? c : 1;
    }
    __syncthreads();   // prob_g writes drained before scatter atomics

    if (t < S_) {
        float pc = __expf(s_scf[t] - M) * invZ;
        atomicAdd(&pred[s_src[t]], pc);
        s_attn[t] = (s_src[t] == ii) ? pc / (float)s_cnt : 0.f;
    }
    __syncthreads();

    const float* eb = encoded + (size_t)b * S_ * 1024;
    for (int d = t; d < 1024; d += 256) {
        float accv = 0.f;
        for (int s2 = 0; s2 < S_; ++s2) {
            float a = s_attn[s2];
            if (a != 0.f) accv += a * eb[s2 * 1024 + d];
        }
        weighted_out[b * 1024 + d] = accv;
    }
}

// ---------------------------------------------------------------------------
extern "C" void kernel_launch(void* const* d_in, const int* in_sizes, int n_in,
                              void* d_out, int out_size, void* d_ws, size_t ws_size,
                              hipStream_t stream)
{
    const int*   input_ids  = (const int*)d_in[0];
    const float* encoded    = (const float*)d_in[1];
    const int*   src        = (const int*)d_in[2];
    const float* prev_state = (const float*)d_in[3];
    const float* weighted   = (const float*)d_in[4];
    const int*   order      = (const int*)d_in[5];
    const float* embed_w    = (const float*)d_in[6];
    const float* gru_w_ih   = (const float*)d_in[7];
    const float* gru_w_hh   = (const float*)d_in[8];
    const float* gru_b_ih   = (const float*)d_in[9];
    const float* gru_b_hh   = (const float*)d_in[10];
    const float* Ws_w       = (const float*)d_in[11];
    const float* Ws_b       = (const float*)d_in[12];
    const float* Wo_w       = (const float*)d_in[13];
    const float* Wo_b       = (const float*)d_in[14];
    const float* Wc_w       = (const float*)d_in[15];
    const float* Wc_b       = (const float*)d_in[16];
    (void)in_sizes; (void)n_in; (void)out_size; (void)ws_size;

    float* predicted    = (float*)d_out;                       // B*V
    float* hidden       = predicted + (size_t)B_ * V_;         // B*H
    float* weighted_out = hidden + (size_t)B_ * H_;            // B*2H

    char* w = (char*)d_ws;
    float* x_f32   = (float*)w;  w += (size_t)B_ * 1536 * 4;
    float* prev_f  = (float*)w;  w += (size_t)B_ * H_ * 4;
    float* gi      = (float*)w;  w += (size_t)B_ * 1536 * 4;
    float* gh      = (float*)w;  w += (size_t)B_ * 1536 * 4;
    float* sc_raw  = (float*)w;  w += (size_t)B_ * S_ * 4;
    float* score_g = (float*)w;  w += (size_t)B_ * V_ * 4;

    hipMemsetAsync(sc_raw, 0, (size_t)B_ * S_ * 4, stream);

    prep_kernel<<<2048, 256, 0, stream>>>(input_ids, encoded, prev_state, weighted,
                                          order, embed_w, Ws_w, Ws_b, x_f32, prev_f);

    // gi = x @ W_ih^T + b_ih   (M=256, N=1536, K=1536)
    gemm_f16<64, 64, 2, 2, 0><<<dim3(1536 / 64, 256 / 64), 256, 0, stream>>>(
        x_f32, gru_w_ih, gi, gru_b_ih, nullptr, nullptr, 1536, 1536, 1536, 1536);
    // gh = prev @ W_hh^T + b_hh  (M=256, N=1536, K=512)
    gemm_f16<64, 64, 2, 2, 0><<<dim3(1536 / 64, 256 / 64), 256, 0, stream>>>(
        prev_f, gru_w_hh, gh, gru_b_hh, nullptr, nullptr, 512, 512, 512, 1536);

    gate_kernel<<<(B_ * H_) / 256, 256, 0, stream>>>(gi, gh, prev_f, hidden);

    // score_g = hidden @ Wo^T + Wo_b   (M=256, N=32000, K=512)
    gemm_f16<256, 64, 4, 1, 0><<<dim3(V_ / 64, 1), 256, 0, stream>>>(
        hidden, Wo_w, score_g, Wo_b, nullptr, nullptr, 512, 512, 512, V_);

    // sc_raw[b,s] = sum_h tanh(enc@Wc^T + Wc_b) * hidden[b,h]  (fused epilogue)
    gemm_f16<128, 128, 2, 2, 1><<<dim3(512 / 128, (B_ * S_) / 128), 256, 0, stream>>>(
        encoded, Wc_w, nullptr, Wc_b, hidden, sc_raw, 1024, 1024, 1024, 0);

    final_kernel<<<B_, 256, 0, stream>>>(score_g, sc_raw, src, input_ids,
                                         encoded, predicted, weighted_out);
}

// Round 2
// 509.836 us; speedup vs baseline: 1.0711x; 1.0711x over previous
//
#include <hip/hip_runtime.h>
#include <cstdint>
#include <cstddef>

#define B_ 256
#define S_ 128
#define H_ 512
#define E_ 512
#define V_ 32000
#define NBLK_G (V_ / 64)   // 500 column blocks in score_g GEMM

typedef _Float16 half_t;
typedef _Float16 half8 __attribute__((ext_vector_type(8)));
typedef float floatx4 __attribute__((ext_vector_type(4)));

__device__ __forceinline__ float sigmoidf_(float x) { return 1.0f / (1.0f + __expf(-x)); }
__device__ __forceinline__ float fast_tanh(float x) {
    float e = __expf(2.0f * x);           // +-inf safe: -> -1 / +1
    return 1.0f - 2.0f / (e + 1.0f);
}

// ---------------------------------------------------------------------------
// prep: x = [embed[ids], weighted_eff] (B,1536), prev_eff (B,512).
// ---------------------------------------------------------------------------
__global__ __launch_bounds__(256)
void prep_kernel(const int* __restrict__ ids, const float* __restrict__ encoded,
                 const float* __restrict__ prev_state, const float* __restrict__ weighted,
                 const int* __restrict__ order_p, const float* __restrict__ embed,
                 const float* __restrict__ Ws_w, const float* __restrict__ Ws_b,
                 float* __restrict__ x, float* __restrict__ prev)
{
    int i = blockIdx.x * 256 + threadIdx.x;   // B_ * 2048 threads
    int b = i >> 11;
    int j = i & 2047;
    int order = order_p[0];
    if (j < 1536) {
        float v;
        if (j < 512) v = embed[(size_t)ids[b] * E_ + j];
        else         v = (order == 0) ? 0.0f : weighted[b * 1024 + (j - 512)];
        x[b * 1536 + j] = v;
    } else {
        int h = j - 1536;
        float v;
        if (order != 0) {
            v = prev_state[b * H_ + h];
        } else {
            const float* e  = encoded + ((size_t)b * S_ + (S_ - 1)) * 1024;
            const float* wr = Ws_w + (size_t)h * 1024;
            float accv = Ws_b[h];
            for (int k = 0; k < 1024; ++k) accv += e[k] * wr[k];
            v = accv;
        }
        prev[b * H_ + h] = v;
    }
}

// ---------------------------------------------------------------------------
// Generic fp32-in / fp16-MFMA GEMM: C[m,n] = sum_k A[m,k]*Bw[n,k] + bias[n]
// XOR-swizzled LDS (no padding, 16-B ops, bank-balanced).
// EPI==0: plain write. EPI==2: write + per-(row, block) softmax partials
//         aux[m*nblk+bx] = rowmax, aux[256*nblk + m*nblk+bx] = sumexp.
// ---------------------------------------------------------------------------
template<int BM, int BN, int WAVES_M, int WAVES_N, int EPI>
__global__ __launch_bounds__(256, 2)
void gemm_f16(const float* __restrict__ A, const float* __restrict__ Bw,
              float* __restrict__ C, const float* __restrict__ bias,
              float* __restrict__ aux, int K, int lda, int ldb, int ldc, int nblk)
{
    constexpr int BK = 32;
    constexpr int WM = BM / WAVES_M;
    constexpr int WN = BN / WAVES_N;
    constexpr int FM = WM / 16;
    constexpr int FN = WN / 16;
    constexpr int A_ITEMS = (BM * 4) / 256;   // items of 8 floats
    constexpr int B_ITEMS = (BN * 4) / 256;

    __shared__ half_t As[BM * BK];
    __shared__ half_t Bs[BN * BK];

    const int tid  = threadIdx.x;
    const int wid  = tid >> 6;
    const int lane = tid & 63;
    const int wm   = wid % WAVES_M;
    const int wn   = wid / WAVES_M;
    const int bm0  = blockIdx.y * BM;
    const int bn0  = blockIdx.x * BN;
    const int col  = lane & 15;
    const int quad = lane >> 4;
    const int swz  = (quad ^ (col & 3)) * 8;

    floatx4 acc[FM][FN] = {};

    for (int kt = 0; kt < K; kt += BK) {
        float4 ar[A_ITEMS][2], br[B_ITEMS][2];
#pragma unroll
        for (int i = 0; i < A_ITEMS; ++i) {
            int idx = tid + i * 256, row = idx >> 2, ch = idx & 3;
            const float* p = A + (size_t)(bm0 + row) * lda + kt + ch * 8;
            ar[i][0] = *(const float4*)p; ar[i][1] = *(const float4*)(p + 4);
        }
#pragma unroll
        for (int i = 0; i < B_ITEMS; ++i) {
            int idx = tid + i * 256, row = idx >> 2, ch = idx & 3;
            const float* p = Bw + (size_t)(bn0 + row) * ldb + kt + ch * 8;
            br[i][0] = *(const float4*)p; br[i][1] = *(const float4*)(p + 4);
        }
        __syncthreads();   // prior iteration's LDS reads done
#pragma unroll
        for (int i = 0; i < A_ITEMS; ++i) {
            int idx = tid + i * 256, row = idx >> 2, ch = idx & 3;
            int pos = (ch ^ (row & 3)) * 8;
            half8 h;
            h[0] = (half_t)ar[i][0].x; h[1] = (half_t)ar[i][0].y;
            h[2] = (half_t)ar[i][0].z; h[3] = (half_t)ar[i][0].w;
            h[4] = (half_t)ar[i][1].x; h[5] = (half_t)ar[i][1].y;
            h[6] = (half_t)ar[i][1].z; h[7] = (half_t)ar[i][1].w;
            *(half8*)(&As[row * BK + pos]) = h;
        }
#pragma unroll
        for (int i = 0; i < B_ITEMS; ++i) {
            int idx = tid + i * 256, row = idx >> 2, ch = idx & 3;
            int pos = (ch ^ (row & 3)) * 8;
            half8 h;
            h[0] = (half_t)br[i][0].x; h[1] = (half_t)br[i][0].y;
            h[2] = (half_t)br[i][0].z; h[3] = (half_t)br[i][0].w;
            h[4] = (half_t)br[i][1].x; h[5] = (half_t)br[i][1].y;
            h[6] = (half_t)br[i][1].z; h[7] = (half_t)br[i][1].w;
            *(half8*)(&Bs[row * BK + pos]) = h;
        }
        __syncthreads();

        half8 af[FM], bf[FN];
#pragma unroll
        for (int fm = 0; fm < FM; ++fm)
            af[fm] = *(const half8*)(&As[(wm * WM + fm * 16 + col) * BK + swz]);
#pragma unroll
        for (int fn = 0; fn < FN; ++fn)
            bf[fn] = *(const half8*)(&Bs[(wn * WN + fn * 16 + col) * BK + swz]);
#pragma unroll
        for (int fm = 0; fm < FM; ++fm)
#pragma unroll
            for (int fn = 0; fn < FN; ++fn)
                acc[fm][fn] = __builtin_amdgcn_mfma_f32_16x16x32_f16(af[fm], bf[fn], acc[fm][fn], 0, 0, 0);
    }

    if constexpr (EPI == 0) {
#pragma unroll
        for (int fm = 0; fm < FM; ++fm) {
            int m0 = bm0 + wm * WM + fm * 16 + quad * 4;
#pragma unroll
            for (int fn = 0; fn < FN; ++fn) {
                int n = bn0 + wn * WN + fn * 16 + col;
                float bv = bias[n];
#pragma unroll
                for (int r = 0; r < 4; ++r)
                    C[(size_t)(m0 + r) * ldc + n] = acc[fm][fn][r] + bv;
            }
        }
    } else {   // EPI == 2 : write + softmax partials (WAVES_N must be 1)
        const int bx = blockIdx.x;
#pragma unroll
        for (int fm = 0; fm < FM; ++fm) {
            int m0 = bm0 + wm * WM + fm * 16 + quad * 4;
            float vv[FN][4];
#pragma unroll
            for (int fn = 0; fn < FN; ++fn) {
                int n = bn0 + fn * 16 + col;
                float bv = bias[n];
#pragma unroll
                for (int r = 0; r < 4; ++r) {
                    vv[fn][r] = acc[fm][fn][r] + bv;
                    C[(size_t)(m0 + r) * ldc + n] = vv[fn][r];
                }
            }
#pragma unroll
            for (int r = 0; r < 4; ++r) {
                float mx = vv[0][r];
#pragma unroll
                for (int fn = 1; fn < FN; ++fn) mx = fmaxf(mx, vv[fn][r]);
#pragma unroll
                for (int off = 1; off < 16; off <<= 1)
                    mx = fmaxf(mx, __shfl_xor(mx, off, 64));
                float se = 0.f;
#pragma unroll
                for (int fn = 0; fn < FN; ++fn) se += __expf(vv[fn][r] - mx);
#pragma unroll
                for (int off = 1; off < 16; off <<= 1)
                    se += __shfl_xor(se, off, 64);
                if (col == 0) {
                    aux[(size_t)(m0 + r) * nblk + bx] = mx;
                    aux[(size_t)256 * nblk + (size_t)(m0 + r) * nblk + bx] = se;
                }
            }
        }
    }
}

// ---------------------------------------------------------------------------
// Wc GEMM + fused tanh-einsum, one block owns ALL N=512:
// sc_out[m] = sum_n tanh(enc[m,:]@Wc[n,:] + bias[n]) * hidden[b(m), n]
// BM=64 rows/block, 512 threads (8 waves, W2xN4), A read from HBM exactly once.
// ---------------------------------------------------------------------------
__global__ __launch_bounds__(512, 2)
void wc_sc_kernel(const float* __restrict__ enc, const float* __restrict__ Wc,
                  const float* __restrict__ bias, const float* __restrict__ hidden,
                  float* __restrict__ sc_out)
{
    constexpr int BK = 32;
    __shared__ half_t As[64 * BK];     //  4 KB
    __shared__ half_t Bs[512 * BK];    // 32 KB
    __shared__ float  s_part[4 * 64];  //  1 KB

    const int tid  = threadIdx.x;
    const int wid  = tid >> 6;
    const int lane = tid & 63;
    const int wm   = wid & 1;          // 2 row-groups of 32
    const int wn   = wid >> 1;         // 4 col-groups of 128
    const int bm0  = blockIdx.x * 64;
    const int col  = lane & 15;
    const int quad = lane >> 4;
    const int swz  = (quad ^ (col & 3)) * 8;

    floatx4 acc[2][8] = {};

    for (int kt = 0; kt < 1024; kt += BK) {
        float4 br[4][2], ar[2];
#pragma unroll
        for (int i = 0; i < 4; ++i) {                 // B: 512 rows
            int idx = tid + i * 512, row = idx >> 2, ch = idx & 3;
            const float* p = Wc + (size_t)row * 1024 + kt + ch * 8;
            br[i][0] = *(const float4*)p; br[i][1] = *(const float4*)(p + 4);
        }
        if (tid < 256) {                              // A: 64 rows
            int row = tid >> 2, ch = tid & 3;
            const float* p = enc + (size_t)(bm0 + row) * 1024 + kt + ch * 8;
            ar[0] = *(const float4*)p; ar[1] = *(const float4*)(p + 4);
        }
        __syncthreads();
#pragma unroll
        for (int i = 0; i < 4; ++i) {
            int idx = tid + i * 512, row = idx >> 2, ch = idx & 3;
            int pos = (ch ^ (row & 3)) * 8;
            half8 h;
            h[0] = (half_t)br[i][0].x; h[1] = (half_t)br[i][0].y;
            h[2] = (half_t)br[i][0].z; h[3] = (half_t)br[i][0].w;
            h[4] = (half_t)br[i][1].x; h[5] = (half_t)br[i][1].y;
            h[6] = (half_t)br[i][1].z; h[7] = (half_t)br[i][1].w;
            *(half8*)(&Bs[row * BK + pos]) = h;
        }
        if (tid < 256) {
            int row = tid >> 2, ch = tid & 3;
            int pos = (ch ^ (row & 3)) * 8;
            half8 h;
            h[0] = (half_t)ar[0].x; h[1] = (half_t)ar[0].y;
            h[2] = (half_t)ar[0].z; h[3] = (half_t)ar[0].w;
            h[4] = (half_t)ar[1].x; h[5] = (half_t)ar[1].y;
            h[6] = (half_t)ar[1].z; h[7] = (half_t)ar[1].w;
            *(half8*)(&As[row * BK + pos]) = h;
        }
        __syncthreads();

        half8 af[2], bf[8];
#pragma unroll
        for (int fm = 0; fm < 2; ++fm)
            af[fm] = *(const half8*)(&As[(wm * 32 + fm * 16 + col) * BK + swz]);
#pragma unroll
        for (int fn = 0; fn < 8; ++fn)
            bf[fn] = *(const half8*)(&Bs[(wn * 128 + fn * 16 + col) * BK + swz]);
#pragma unroll
        for (int fm = 0; fm < 2; ++fm)
#pragma unroll
            for (int fn = 0; fn < 8; ++fn)
                acc[fm][fn] = __builtin_amdgcn_mfma_f32_16x16x32_f16(af[fm], bf[fn], acc[fm][fn], 0, 0, 0);
    }

    // fused epilogue: tanh + dot with hidden, reduce over n
    const float* hid = hidden + (size_t)(bm0 >> 7) * H_;
#pragma unroll
    for (int fm = 0; fm < 2; ++fm) {
        float p0 = 0.f, p1 = 0.f, p2 = 0.f, p3 = 0.f;
#pragma unroll
        for (int fn = 0; fn < 8; ++fn) {
            int n = wn * 128 + fn * 16 + col;
            float bv = bias[n];
            float hv = hid[n];
            p0 += fast_tanh(acc[fm][fn][0] + bv) * hv;
            p1 += fast_tanh(acc[fm][fn][1] + bv) * hv;
            p2 += fast_tanh(acc[fm][fn][2] + bv) * hv;
            p3 += fast_tanh(acc[fm][fn][3] + bv) * hv;
        }
#pragma unroll
        for (int off = 1; off < 16; off <<= 1) {
            p0 += __shfl_xor(p0, off, 64);
            p1 += __shfl_xor(p1, off, 64);
            p2 += __shfl_xor(p2, off, 64);
            p3 += __shfl_xor(p3, off, 64);
        }
        if (col == 0) {
            int rloc = wm * 32 + fm * 16 + quad * 4;   // [0,64)
            s_part[wn * 64 + rloc + 0] = p0;
            s_part[wn * 64 + rloc + 1] = p1;
            s_part[wn * 64 + rloc + 2] = p2;
            s_part[wn * 64 + rloc + 3] = p3;
        }
    }
    __syncthreads();
    if (tid < 64) {
        float s = s_part[tid] + s_part[64 + tid] + s_part[128 + tid] + s_part[192 + tid];
        sc_out[bm0 + tid] = s;
    }
}

// ---------------------------------------------------------------------------
// GRU gates
// ---------------------------------------------------------------------------
__global__ __launch_bounds__(256)
void gate_kernel(const float* __restrict__ gi, const float* __restrict__ gh,
                 const float* __restrict__ prev, float* __restrict__ hidden)
{
    int i = blockIdx.x * 256 + threadIdx.x;   // B_*H_
    int b = i >> 9;
    int h = i & 511;
    const float* gib = gi + (size_t)b * 1536;
    const float* ghb = gh + (size_t)b * 1536;
    float r = sigmoidf_(gib[h] + ghb[h]);
    float z = sigmoidf_(gib[h + 512] + ghb[h + 512]);
    float n = tanhf(gib[h + 1024] + r * ghb[h + 1024]);
    hidden[i] = (1.0f - z) * n + z * prev[i];
}

// ---------------------------------------------------------------------------
// final: merge softmax partials (from score_g GEMM epilogue) + copy scores,
// single in-place exp pass over predicted (float4), scatter, weighted_out.
// ---------------------------------------------------------------------------
__global__ __launch_bounds__(256)
void final_kernel(const float* __restrict__ sc_raw,
                  const int* __restrict__ src, const int* __restrict__ ids,
                  const float* __restrict__ encoded, const float* __restrict__ parts,
                  float* __restrict__ predicted, float* __restrict__ weighted_out)
{
    int b = blockIdx.x;
    int t = threadIdx.x;
    __shared__ float s_scf[S_];
    __shared__ float s_attn[S_];
    __shared__ int   s_src[S_];
    __shared__ float rm[4], rs[4];
    __shared__ int   s_cnt;

    float* pred = predicted + (size_t)b * V_;
    const float* pm = parts + (size_t)b * NBLK_G;
    const float* ps = parts + (size_t)256 * NBLK_G + (size_t)b * NBLK_G;

    if (t < S_) {
        int sv = src[b * S_ + t];
        s_src[t] = sv;
        float raw = sc_raw[b * S_ + t];
        if (sv == 0) raw -= 1000.0f;
        s_scf[t] = tanhf(raw);
    }

    // merge (max, sumexp) partials
    float m = -1e30f, s = 0.f;
    for (int j = t; j < NBLK_G; j += 256) {
        float mo = pm[j], so = ps[j];
        float mn = fmaxf(m, mo);
        s = s * __expf(m - mn) + so * __expf(mo - mn);
        m = mn;
    }
    __syncthreads();
    if (t < S_) {
        float x = s_scf[t];
        float mn = fmaxf(m, x);
        s = s * __expf(m - mn) + __expf(x - mn);
        m = mn;
    }
#pragma unroll
    for (int off = 1; off < 64; off <<= 1) {
        float mo = __shfl_xor(m, off, 64);
        float so = __shfl_xor(s, off, 64);
        float mn = fmaxf(m, mo);
        s = s * __expf(m - mn) + so * __expf(mo - mn);
        m = mn;
    }
    if ((t & 63) == 0) { rm[t >> 6] = m; rs[t >> 6] = s; }
    __syncthreads();
    float M = rm[0], Z = rs[0];
#pragma unroll
    for (int w = 1; w < 4; ++w) {
        float mo = rm[w], so = rs[w];
        float mn = fmaxf(M, mo);
        Z = Z * __expf(M - mn) + so * __expf(mo - mn);
        M = mn;
    }
    float invZ = 1.0f / Z;

    // in-place: predicted currently holds score_g
    float4* pr4 = (float4*)pred;
    for (int i = t; i < V_ / 4; i += 256) {
        float4 x = pr4[i];
        float4 o;
        o.x = __expf(x.x - M) * invZ;
        o.y = __expf(x.y - M) * invZ;
        o.z = __expf(x.z - M) * invZ;
        o.w = __expf(x.w - M) * invZ;
        pr4[i] = o;
    }

    int ii = ids[b];
    if (t == 0) {
        int c = 0;
        for (int s2 = 0; s2 < S_; ++s2) c += (s_src[s2] == ii) ? 1 : 0;
        s_cnt = (c > 0) ? c : 1;
    }
    __syncthreads();   // prob_g writes drained before scatter atomics

    if (t < S_) {
        float pc = __expf(s_scf[t] - M) * invZ;
        atomicAdd(&pred[s_src[t]], pc);
        s_attn[t] = (s_src[t] == ii) ? pc / (float)s_cnt : 0.f;
    }
    __syncthreads();

    const float* eb = encoded + (size_t)b * S_ * 1024;
    for (int d = t; d < 1024; d += 256) {
        float accv = 0.f;
        for (int s2 = 0; s2 < S_; ++s2) {
            float a = s_attn[s2];
            if (a != 0.f) accv += a * eb[s2 * 1024 + d];
        }
        weighted_out[b * 1024 + d] = accv;
    }
}

// ---------------------------------------------------------------------------
extern "C" void kernel_launch(void* const* d_in, const int* in_sizes, int n_in,
                              void* d_out, int out_size, void* d_ws, size_t ws_size,
                              hipStream_t stream)
{
    const int*   input_ids  = (const int*)d_in[0];
    const float* encoded    = (const float*)d_in[1];
    const int*   src        = (const int*)d_in[2];
    const float* prev_state = (const float*)d_in[3];
    const float* weighted   = (const float*)d_in[4];
    const int*   order      = (const int*)d_in[5];
    const float* embed_w    = (const float*)d_in[6];
    const float* gru_w_ih   = (const float*)d_in[7];
    const float* gru_w_hh   = (const float*)d_in[8];
    const float* gru_b_ih   = (const float*)d_in[9];
    const float* gru_b_hh   = (const float*)d_in[10];
    const float* Ws_w       = (const float*)d_in[11];
    const float* Ws_b       = (const float*)d_in[12];
    const float* Wo_w       = (const float*)d_in[13];
    const float* Wo_b       = (const float*)d_in[14];
    const float* Wc_w       = (const float*)d_in[15];
    const float* Wc_b       = (const float*)d_in[16];
    (void)in_sizes; (void)n_in; (void)out_size; (void)ws_size;

    float* predicted    = (float*)d_out;                       // B*V (holds score_g first)
    float* hidden       = predicted + (size_t)B_ * V_;         // B*H
    float* weighted_out = hidden + (size_t)B_ * H_;            // B*2H

    char* w = (char*)d_ws;
    float* x_f32  = (float*)w;  w += (size_t)B_ * 1536 * 4;
    float* prev_f = (float*)w;  w += (size_t)B_ * H_ * 4;
    float* gi     = (float*)w;  w += (size_t)B_ * 1536 * 4;
    float* gh     = (float*)w;  w += (size_t)B_ * 1536 * 4;
    float* sc_raw = (float*)w;  w += (size_t)B_ * S_ * 4;
    float* parts  = (float*)w;  w += (size_t)2 * B_ * NBLK_G * 4;

    prep_kernel<<<2048, 256, 0, stream>>>(input_ids, encoded, prev_state, weighted,
                                          order, embed_w, Ws_w, Ws_b, x_f32, prev_f);

    // gi = x @ W_ih^T + b_ih   (M=256, N=1536, K=1536)
    gemm_f16<64, 64, 2, 2, 0><<<dim3(1536 / 64, 256 / 64), 256, 0, stream>>>(
        x_f32, gru_w_ih, gi, gru_b_ih, nullptr, 1536, 1536, 1536, 1536, 0);
    // gh = prev @ W_hh^T + b_hh  (M=256, N=1536, K=512)
    gemm_f16<64, 64, 2, 2, 0><<<dim3(1536 / 64, 256 / 64), 256, 0, stream>>>(
        prev_f, gru_w_hh, gh, gru_b_hh, nullptr, 512, 512, 512, 1536, 0);

    gate_kernel<<<(B_ * H_) / 256, 256, 0, stream>>>(gi, gh, prev_f, hidden);

    // sc_raw[b,s] (fused tanh-einsum), encoded read exactly once
    wc_sc_kernel<<<(B_ * S_) / 64, 512, 0, stream>>>(encoded, Wc_w, Wc_b, hidden, sc_raw);

    // score_g -> predicted (in-place later) + softmax partials
    gemm_f16<256, 64, 4, 1, 2><<<dim3(NBLK_G, 1), 256, 0, stream>>>(
        hidden, Wo_w, predicted, Wo_b, parts, 512, 512, 512, V_, NBLK_G);

    final_kernel<<<B_, 256, 0, stream>>>(sc_raw, src, input_ids, encoded, parts,
                                         predicted, weighted_out);
}